// Round 15
// baseline (284.651 us; speedup 1.0000x reference)
//
#include <hip/hip_runtime.h>
#include <stdint.h>

#define N_NODES 50000
#define M_PAD   50048   // 391*128
#define NIN     512
#define HDIM    512
#define DDIM    128
#define A_ADJ   3
#define E_EDGES 800000
#define TOT_E   (A_ADJ * E_EDGES)           // 2,400,000
#define TOT_ROWS (A_ADJ * N_NODES)          // 150,000
#define CB      49                          // coarse bins per adjacency (1024 rows each)
#define NB      (A_ADJ * CB)                // 147
#define CAP     17664                       // bin capacity: lambda=16384 + ~10 sigma
#define CHUNK   2048
#define NCHB    ((TOT_E + CHUNK - 1) / CHUNK)   // 1172
#define TRB     640                         // transpose blocks (163840/256)
#define DIB     25000                       // dropin blocks (6.4M/256)
#define G0NWG   (4 * (M_PAD / 128))         // 1564 gemm0 blocks

typedef __bf16 bf16x8 __attribute__((ext_vector_type(8)));
typedef float  f32x4  __attribute__((ext_vector_type(4)));
typedef const __attribute__((address_space(1))) void* gas1_t;
typedef __attribute__((address_space(3))) void* las3_t;

// ---------------- JAX threefry2x32 (bit-exact, partitionable mode) ----------------
__host__ __device__ inline void tf_round(uint32_t& x0, uint32_t& x1, int r) {
  x0 += x1; x1 = (x1 << r) | (x1 >> (32 - r)); x1 ^= x0;
}
__host__ __device__ inline void threefry2x32(uint32_t k0, uint32_t k1,
                                             uint32_t x0, uint32_t x1,
                                             uint32_t& o0, uint32_t& o1) {
  uint32_t ks2 = k0 ^ k1 ^ 0x1BD11BDAu;
  x0 += k0; x1 += k1;
  tf_round(x0,x1,13); tf_round(x0,x1,15); tf_round(x0,x1,26); tf_round(x0,x1,6);
  x0 += k1; x1 += ks2 + 1u;
  tf_round(x0,x1,17); tf_round(x0,x1,29); tf_round(x0,x1,16); tf_round(x0,x1,24);
  x0 += ks2; x1 += k0 + 2u;
  tf_round(x0,x1,13); tf_round(x0,x1,15); tf_round(x0,x1,26); tf_round(x0,x1,6);
  x0 += k0; x1 += k1 + 3u;
  tf_round(x0,x1,17); tf_round(x0,x1,29); tf_round(x0,x1,16); tf_round(x0,x1,24);
  x0 += k1; x1 += ks2 + 4u;
  tf_round(x0,x1,13); tf_round(x0,x1,15); tf_round(x0,x1,26); tf_round(x0,x1,6);
  x0 += ks2; x1 += k0 + 5u;
  o0 = x0; o1 = x1;
}

__device__ inline bool keep_bit(uint32_t b) {
  float f = __uint_as_float((b >> 9) | 0x3f800000u) - 1.0f;
  return f < 0.8f;
}
__device__ inline uint16_t f2bf(float f) {           // RNE float->bf16
  uint32_t u = __float_as_uint(f);
  return (uint16_t)((u + 0x7fffu + ((u >> 16) & 1u)) >> 16);
}
__device__ inline float bf2f(uint16_t b) { return __uint_as_float(((uint32_t)b) << 16); }

__device__ inline uint32_t rbits32(uint32_t ka, uint32_t kb, uint32_t i) {
  uint32_t o0, o1;
  threefry2x32(ka, kb, 0u, i, o0, o1);
  return o0 ^ o1;
}

// ---------------- GEMM body: 128x128 tile, 2-phase dbuf + source-side XOR swizzle ----------------
// MODE 0: relu -> bf16 h.  MODE 1: f32 h_a + fused drop2 -> bf16 hp0.
template <int MODE>
__device__ __forceinline__ void gemm_body(const uint16_t* __restrict__ A,
                                          const uint16_t* __restrict__ Bt,
                                          const float* __restrict__ bias,
                                          uint16_t* __restrict__ hOut,
                                          float* __restrict__ fOut,
                                          uint16_t* __restrict__ hp0,
                                          int Nn, int K, int bx, int by,
                                          char* smem, uint32_t ka, uint32_t kb) {
  uint16_t* As0 = (uint16_t*)smem;                    // 2 x 8 KB A, 2 x 8 KB B
  uint16_t* Bs0 = As0 + 8192;
  const int t  = threadIdx.x;
  const int w  = t >> 6, l = t & 63;
  const int lm = l & 15, kg = l >> 4;
  const int wr = w >> 1, wc = w & 1;
  const int rowbase = by * 128;
  const int colbase = bx * 128;
  const int c0 = t, c1 = t + 256;
  const int n0 = c0 >> 2, ch0 = (c0 & 3) ^ ((n0 >> 1) & 3);
  const int n1 = c1 >> 2, ch1 = (c1 & 3) ^ ((n1 >> 1) & 3);

  f32x4 acc[4][4] = {};

#define STAGEB(buf, kt)                                                             \
  {                                                                                 \
    __builtin_amdgcn_global_load_lds(                                               \
        (gas1_t)&A [(size_t)(rowbase + n0) * K + (kt) + ch0 * 8],                   \
        (las3_t)(As0 + (buf) * 4096 + c0 * 8), 16, 0, 0);                           \
    __builtin_amdgcn_global_load_lds(                                               \
        (gas1_t)&A [(size_t)(rowbase + n1) * K + (kt) + ch1 * 8],                   \
        (las3_t)(As0 + (buf) * 4096 + c1 * 8), 16, 0, 0);                           \
    __builtin_amdgcn_global_load_lds(                                               \
        (gas1_t)&Bt[(size_t)(colbase + n0) * K + (kt) + ch0 * 8],                   \
        (las3_t)(Bs0 + (buf) * 4096 + c0 * 8), 16, 0, 0);                           \
    __builtin_amdgcn_global_load_lds(                                               \
        (gas1_t)&Bt[(size_t)(colbase + n1) * K + (kt) + ch1 * 8],                   \
        (las3_t)(Bs0 + (buf) * 4096 + c1 * 8), 16, 0, 0);                           \
  }

  STAGEB(0, 0);
  asm volatile("s_waitcnt vmcnt(0)" ::: "memory");
  __syncthreads();

  const int NT = K >> 5;
  for (int tt = 0; tt < NT; ++tt) {
    const int cur = tt & 1;
    if (tt + 1 < NT) STAGEB(cur ^ 1, (tt + 1) * 32);

    const uint16_t* Asc = As0 + cur * 4096;
    const uint16_t* Bsc = Bs0 + cur * 4096;
    bf16x8 af[4], bfr[4];
#pragma unroll
    for (int m = 0; m < 4; ++m) {
      int ra = wr * 64 + m * 16 + lm;
      af[m] = *(const bf16x8*)&Asc[ra * 32 + ((kg ^ ((ra >> 1) & 3)) << 3)];
    }
#pragma unroll
    for (int n = 0; n < 4; ++n) {
      int rb = wc * 64 + n * 16 + lm;
      bfr[n] = *(const bf16x8*)&Bsc[rb * 32 + ((kg ^ ((rb >> 1) & 3)) << 3)];
    }
#pragma unroll
    for (int m = 0; m < 4; ++m)
#pragma unroll
      for (int n = 0; n < 4; ++n)
        acc[m][n] = __builtin_amdgcn_mfma_f32_16x16x32_bf16(af[m], bfr[n], acc[m][n], 0, 0, 0);

    asm volatile("s_waitcnt vmcnt(0)" ::: "memory");   // next-tile loads landed
    __syncthreads();                                   // all waves done with cur
  }
#undef STAGEB

#pragma unroll
  for (int m = 0; m < 4; ++m) {
    int r0 = rowbase + wr * 64 + m * 16 + kg * 4;
#pragma unroll
    for (int n = 0; n < 4; ++n) {
      int cc = colbase + wc * 64 + n * 16 + lm;
      float bv = bias[cc];
#pragma unroll
      for (int r = 0; r < 4; ++r) {
        int row = r0 + r;
        if (row < N_NODES) {
          float v = acc[m][n][r] + bv;
          if (MODE == 0) {
            hOut[(size_t)row * Nn + cc] = f2bf(fmaxf(v, 0.0f));
          } else {
            fOut[(size_t)row * Nn + cc] = v;
            uint32_t bits = rbits32(ka, kb, (uint32_t)(row * DDIM + cc));
            hp0[(size_t)row * DDIM + cc] = f2bf(keep_bit(bits) ? v * 1.25f : 0.0f);
          }
        }
      }
    }
  }
}

// ---------------- pass 1 body: chunk-sort 2048 edges into padded bin arenas ----------------
struct P1S {
  uint64_t lbuf[CHUNK];                               // 16384 B
  uint16_t lbkt[CHUNK];                               // 4096 B
  uint32_t hist[NB], scn[NB], lofs[NB], base[NB];     // 2352 B
  uint32_t hs[256];                                   // 1024 B
};                                                    // ~23.9 KB

__device__ __forceinline__ void pass1_body(const int* __restrict__ rows,
                                           const int* __restrict__ cols,
                                           const float* __restrict__ vals,
                                           uint32_t* __restrict__ gcur,
                                           uint64_t* __restrict__ sedgeA,
                                           int blk, char* smem) {
  P1S* S = (P1S*)smem;
  const int tid = threadIdx.x;
  const int cb = blk * CHUNK;
  const int cnt = min(CHUNK, TOT_E - cb);

  if (tid < NB) S->hist[tid] = 0;
  __syncthreads();

  uint64_t pay[8];
  uint16_t bk[8];
#pragma unroll
  for (int c = 0; c < 8; ++c) {
    int p = tid + c * 256;
    bk[c] = 0xffffu;
    if (p < cnt) {
      int e = cb + p;
      int a = e / E_EDGES;
      uint32_t r   = (uint32_t)rows[e];
      uint32_t col = (uint32_t)cols[e];
      float    v   = vals[e];
      uint16_t b = (uint16_t)(a * CB + (r >> 10));
      pay[c] = ((uint64_t)__float_as_uint(v) << 32) | ((r & 1023u) << 16) | col;
      bk[c]  = b;
      atomicAdd(&S->hist[b], 1u);
    }
  }
  __syncthreads();

  uint32_t hv = (tid < NB) ? S->hist[tid] : 0u;
  S->hs[tid] = hv;
  __syncthreads();
  for (int off = 1; off < 256; off <<= 1) {
    uint32_t v = (tid >= off) ? S->hs[tid - off] : 0u;
    __syncthreads();
    S->hs[tid] += v;
    __syncthreads();
  }
  if (tid < NB) {
    uint32_t excl = S->hs[tid] - hv;
    S->scn[tid]  = excl;
    S->lofs[tid] = excl;
    S->base[tid] = (uint32_t)tid * CAP + (hv ? atomicAdd(&gcur[tid], hv) : 0u);
  }
  __syncthreads();

#pragma unroll
  for (int c = 0; c < 8; ++c) {
    if (bk[c] != 0xffffu) {
      uint32_t p = atomicAdd(&S->lofs[bk[c]], 1u);
      S->lbuf[p] = pay[c];
      S->lbkt[p] = bk[c];
    }
  }
  __syncthreads();

#pragma unroll
  for (int c = 0; c < 8; ++c) {
    int p = tid + c * 256;
    if (p < cnt) {
      uint16_t k = S->lbkt[p];
      uint32_t slot = S->base[k] + ((uint32_t)p - S->scn[k]);
      if (slot < (uint32_t)(k + 1) * CAP)             // ~10-sigma guard, never taken
        sedgeA[slot] = S->lbuf[p];
    }
  }
}

// ---------------- pass 2 body: per bin, exact row sort -> u32 edges + offs/ends ----------------
struct P2S { uint32_t rh[1024], rs[1024], wsum[256]; };   // 9216 B

__device__ __forceinline__ void pass2_body(const uint32_t* __restrict__ gcur,
                                           const uint64_t* __restrict__ sedgeA,
                                           uint32_t* __restrict__ sedgeB,
                                           uint32_t* __restrict__ offs,
                                           uint32_t* __restrict__ ends,
                                           int b, char* smem) {
  P2S* S = (P2S*)smem;
  const int tid = threadIdx.x;
  const int a = b / CB, rb = (b % CB) * 1024;
  const int nrows = min(1024, N_NODES - rb);
  const uint32_t s0 = (uint32_t)b * CAP;
  uint32_t count = gcur[b];
  if (count > CAP) count = CAP;
  const uint32_t e0 = s0 + count;

#pragma unroll
  for (int c = 0; c < 4; ++c) S->rh[tid + c * 256] = 0;
  __syncthreads();
  for (uint32_t i = s0 + tid; i < e0; i += 256) {
    uint32_t rl = ((uint32_t)(sedgeA[i] >> 16)) & 1023u;
    atomicAdd(&S->rh[rl], 1u);
  }
  __syncthreads();

  uint32_t c0 = S->rh[tid * 4], c1 = S->rh[tid * 4 + 1];
  uint32_t c2 = S->rh[tid * 4 + 2], c3 = S->rh[tid * 4 + 3];
  uint32_t tsum = c0 + c1 + c2 + c3;
  S->wsum[tid] = tsum;
  __syncthreads();
  for (int off = 1; off < 256; off <<= 1) {
    uint32_t v = (tid >= off) ? S->wsum[tid - off] : 0u;
    __syncthreads();
    S->wsum[tid] += v;
    __syncthreads();
  }
  uint32_t run = S->wsum[tid] - tsum;
  S->rs[tid * 4] = run;     run += c0;
  S->rs[tid * 4 + 1] = run; run += c1;
  S->rs[tid * 4 + 2] = run; run += c2;
  S->rs[tid * 4 + 3] = run;
  __syncthreads();

  // per-row offs/ends (padded bases) + reset cursors
  for (int r = tid; r < 1024; r += 256) {
    if (r < nrows) {
      uint32_t st = s0 + S->rs[r];
      offs[(size_t)a * N_NODES + rb + r] = st;
      uint32_t cn = (r + 1 < 1024) ? (S->rs[r + 1] - S->rs[r]) : (count - S->rs[r]);
      ends[(size_t)a * N_NODES + rb + r] = st + cn;
    }
    S->rh[r] = S->rs[r];
  }
  __syncthreads();

  // exact scatter within the bin's span; convert to u32 {bf16 val | u16 col}
  for (uint32_t i = s0 + tid; i < e0; i += 256) {
    uint64_t ed = sedgeA[i];
    uint32_t rl = ((uint32_t)(ed >> 16)) & 1023u;
    uint32_t p = atomicAdd(&S->rh[rl], 1u);
    uint32_t vb = (uint32_t)f2bf(__uint_as_float((uint32_t)(ed >> 32)));
    sedgeB[s0 + p] = (vb << 16) | ((uint32_t)ed & 0xffffu);
  }
}

// ---------------- K1: transpose2 || pass1 || dropin (all independent) ----------------
__global__ __launch_bounds__(256) void k_front(const float* __restrict__ W1,
                                               uint16_t* __restrict__ w1t,
                                               const float* __restrict__ W2,
                                               uint16_t* __restrict__ w2t,
                                               const float* __restrict__ seq,
                                               uint16_t* __restrict__ x,
                                               const int* __restrict__ rows,
                                               const int* __restrict__ cols,
                                               const float* __restrict__ vals,
                                               uint32_t* __restrict__ gcur,
                                               uint64_t* __restrict__ sedgeA,
                                               uint32_t ka, uint32_t kb) {
  __shared__ __align__(16) char smem[24576];
  const int b = blockIdx.x, tid = threadIdx.x;
  if (b < TRB) {                                      // weight transposes
    int t = b * 256 + tid;
    const int T1 = (NIN * HDIM) / 2;
    if (t < T1) {
      int k2 = (2 * t) % NIN, n = (2 * t) / NIN;
      uint32_t p = (uint32_t)f2bf(W1[(size_t)k2 * HDIM + n])
                 | ((uint32_t)f2bf(W1[(size_t)(k2 + 1) * HDIM + n]) << 16);
      *(uint32_t*)&w1t[(size_t)n * NIN + k2] = p;
    } else {
      int u = t - T1;
      int k2 = (2 * u) % HDIM, n = (2 * u) / HDIM;
      uint32_t p = (uint32_t)f2bf(W2[(size_t)k2 * DDIM + n])
                 | ((uint32_t)f2bf(W2[(size_t)(k2 + 1) * DDIM + n]) << 16);
      *(uint32_t*)&w2t[(size_t)n * HDIM + k2] = p;
    }
  } else if (b < TRB + NCHB) {                        // edge partition pass 1
    pass1_body(rows, cols, vals, gcur, sedgeA, b - TRB, smem);
  } else {                                            // input dropout
    int t = (b - TRB - NCHB) * 256 + tid;             // < 6.4M exactly
    int i0 = 4 * t;
    float4 v = ((const float4*)seq)[t];
    float f[4] = {v.x, v.y, v.z, v.w};
    uint16_t r[4];
#pragma unroll
    for (int j = 0; j < 4; ++j) {
      uint32_t bits = rbits32(ka, kb, (uint32_t)(i0 + j));
      r[j] = f2bf(keep_bit(bits) ? f[j] * 1.25f : 0.0f);
    }
    uint2 w;
    w.x = (uint32_t)r[0] | ((uint32_t)r[1] << 16);
    w.y = (uint32_t)r[2] | ((uint32_t)r[3] << 16);
    ((uint2*)x)[t] = w;
  }
}

// ---------------- K2: gemm0 (bijective XCD chunk swizzle, m204) ----------------
__global__ __launch_bounds__(256) void k_mid(const uint16_t* __restrict__ x,
                                             const uint16_t* __restrict__ w1t,
                                             const float* __restrict__ b1,
                                             uint16_t* __restrict__ h) {
  __shared__ __align__(16) char smem[32768];
  // map hardware block id -> logical tile id so each XCD gets a CONTIGUOUS
  // chunk of logical ids (consecutive logical ids share the same x row-panel).
  const int q = G0NWG >> 3, r = G0NWG & 7;            // 195, 4
  int xcd = blockIdx.x & 7, o = blockIdx.x >> 3;
  int wg = (xcd < r) ? xcd * (q + 1) + o : r * (q + 1) + (xcd - r) * q + o;
  gemm_body<0>(x, w1t, b1, h, nullptr, nullptr, HDIM, NIN, wg & 3, wg >> 2, smem, 0u, 0u);
}

// ---------------- K3: gemm1(+drop2) || pass2 ----------------
__global__ __launch_bounds__(256) void k_back(const uint16_t* __restrict__ h,
                                              const uint16_t* __restrict__ w2t,
                                              const float* __restrict__ b2,
                                              float* __restrict__ ha,
                                              uint16_t* __restrict__ hp0,
                                              const uint32_t* __restrict__ gcur,
                                              const uint64_t* __restrict__ sedgeA,
                                              uint32_t* __restrict__ sedgeB,
                                              uint32_t* __restrict__ offs,
                                              uint32_t* __restrict__ ends,
                                              uint32_t ka, uint32_t kb) {
  __shared__ __align__(16) char smem[32768];
  const int b = blockIdx.x;
  if (b < M_PAD / 128)                                 // 391 gemm1 blocks
    gemm_body<1>(h, w2t, b2, nullptr, ha, hp0, DDIM, HDIM, 0, b, smem, ka, kb);
  else
    pass2_body(gcur, sedgeA, sedgeB, offs, ends, b - M_PAD / 128, smem);
}

// ---------------- SpMM+fusion: one wave per row, 4-deep gather (16 edges/iter) ----------------
__global__ __launch_bounds__(256) void k_spmm_csr3(const uint32_t* __restrict__ offs,
                                                   const uint32_t* __restrict__ ends,
                                                   const uint32_t* __restrict__ sedge,
                                                   const uint16_t* __restrict__ hp0,
                                                   float* __restrict__ stack,
                                                   float* __restrict__ fus) {
  int row = (int)((blockIdx.x * (size_t)blockDim.x + threadIdx.x) >> 6);
  int l = threadIdx.x & 63;
  if (row >= N_NODES) return;
  const int q = l & 15, g = l >> 4;
  const char* hpb = (const char*)hp0;
  const uint32_t qoff = (uint32_t)(q << 4);           // 32-bit gather addressing
  float fs[8] = {};

#pragma unroll
  for (int a = 0; a < A_ADJ; ++a) {
    uint32_t s = offs[(size_t)a * N_NODES + row];
    uint32_t e = ends[(size_t)a * N_NODES + row];
    float acc[8] = {};
    for (uint32_t i = s; i < e; i += 16) {
      float vv[4] = {0.f, 0.f, 0.f, 0.f};
      uint32_t oo[4] = {qoff, qoff, qoff, qoff};
#pragma unroll
      for (int j = 0; j < 4; ++j) {
        uint32_t ij = i + j * 4 + g;
        if (ij < e) {
          uint32_t ed = sedge[ij];
          oo[j] += (ed & 0xffffu) << 8;
          vv[j] = bf2f((uint16_t)(ed >> 16));
        }
      }
      uint4 p[4];
#pragma unroll
      for (int j = 0; j < 4; ++j) p[j] = *(const uint4*)(hpb + oo[j]);
#pragma unroll
      for (int j = 0; j < 4; ++j) {
        acc[0] += bf2f((uint16_t)(p[j].x & 0xffffu)) * vv[j];
        acc[1] += bf2f((uint16_t)(p[j].x >> 16)) * vv[j];
        acc[2] += bf2f((uint16_t)(p[j].y & 0xffffu)) * vv[j];
        acc[3] += bf2f((uint16_t)(p[j].y >> 16)) * vv[j];
        acc[4] += bf2f((uint16_t)(p[j].z & 0xffffu)) * vv[j];
        acc[5] += bf2f((uint16_t)(p[j].z >> 16)) * vv[j];
        acc[6] += bf2f((uint16_t)(p[j].w & 0xffffu)) * vv[j];
        acc[7] += bf2f((uint16_t)(p[j].w >> 16)) * vv[j];
      }
    }
#pragma unroll
    for (int d = 0; d < 8; ++d) {
      acc[d] += __shfl_xor(acc[d], 16);
      acc[d] += __shfl_xor(acc[d], 32);
    }
    if (l < 16) {
      size_t b4 = ((size_t)a * N_NODES + row) * 32 + (size_t)q * 2;
      ((float4*)stack)[b4]     = make_float4(acc[0], acc[1], acc[2], acc[3]);
      ((float4*)stack)[b4 + 1] = make_float4(acc[4], acc[5], acc[6], acc[7]);
    }
#pragma unroll
    for (int d = 0; d < 8; ++d) fs[d] += acc[d];
  }
  if (l < 16) {
    const float k3 = 1.0f / 3.0f;
    size_t b4 = (size_t)row * 32 + (size_t)q * 2;
    ((float4*)fus)[b4]     = make_float4(fs[0] * k3, fs[1] * k3, fs[2] * k3, fs[3] * k3);
    ((float4*)fus)[b4 + 1] = make_float4(fs[4] * k3, fs[5] * k3, fs[6] * k3, fs[7] * k3);
  }
}

extern "C" void kernel_launch(void* const* d_in, const int* in_sizes, int n_in,
                              void* d_out, int out_size, void* d_ws, size_t ws_size,
                              hipStream_t stream) {
  const float* seq  = (const float*)d_in[0];
  const float* W1   = (const float*)d_in[1];
  const float* b1   = (const float*)d_in[2];
  const float* W2   = (const float*)d_in[3];
  const float* b2   = (const float*)d_in[4];
  const float* vals = (const float*)d_in[5];
  const int*   rows = (const int*)d_in[6];
  const int*   cols = (const int*)d_in[7];

  float* out       = (float*)d_out;
  float* out_ha    = out;                                       // [N, D]
  float* out_stack = out + (size_t)N_NODES * DDIM;              // [A, N, D]
  float* out_fus   = out_stack + (size_t)A_ADJ * N_NODES * DDIM;

  uint16_t* x   = (uint16_t*)d_ws;                              // [M_PAD, NIN]  51.2 MB
  uint16_t* h   = x   + (size_t)M_PAD * NIN;                    // [M_PAD, HDIM] 51.2 MB
  uint16_t* w1t = h   + (size_t)M_PAD * HDIM;                   // [HDIM, NIN]
  uint16_t* w2t = w1t + (size_t)HDIM * NIN;                     // [DDIM, HDIM]
  uint16_t* hp0 = w2t + (size_t)DDIM * HDIM;                    // [N, D]
  uint32_t* gcur = (uint32_t*)(hp0 + (size_t)N_NODES * DDIM);   // [NB] (outside x!)
  uint32_t* offs = gcur + 256;                                  // [TOT_ROWS]
  uint32_t* ends = offs + TOT_ROWS;                             // [TOT_ROWS]

  // sedgeA (u64, padded arena 147*CAP = 20.8 MB) lives in d_out's stack region
  // (dead until spmm fully rewrites it); sedgeB (u32, 10.4 MB) aliases x
  // (dead after k_mid; pass2 runs in k_back).
  uint64_t* sedgeA = (uint64_t*)out_stack;
  uint32_t* sedgeB = (uint32_t*)x;

  // JAX partitionable-mode split of key (0,42)
  uint32_t k0a, k0b, k1a, k1b;
  threefry2x32(0u, 42u, 0u, 0u, k0a, k0b);
  threefry2x32(0u, 42u, 0u, 1u, k1a, k1b);

  (void)hipMemsetAsync(gcur, 0, NB * sizeof(uint32_t), stream);

  // K1: transposes || pass1 (padded-arena scatter) || dropin
  k_front<<<TRB + NCHB + DIB, 256, 0, stream>>>(W1, w1t, W2, w2t, seq, x,
                                                rows, cols, vals, gcur, sedgeA, k0a, k0b);

  // K2: gemm0 (XCD-chunked)
  k_mid<<<G0NWG, 256, 0, stream>>>(x, w1t, b1, h);

  // K3: gemm1(+drop2) || pass2
  k_back<<<(M_PAD / 128) + NB, 256, 0, stream>>>(h, w2t, b2, out_ha, hp0,
                                                 gcur, sedgeA, sedgeB, offs, ends, k1a, k1b);

  // SpMM + fused mean (overwrites the sedgeA region with real stack values)
  k_spmm_csr3<<<(N_NODES * 64 + 255) / 256, 256, 0, stream>>>(offs, ends, sedgeB, hp0,
                                                              out_stack, out_fus);
}

// Round 16
// 267.444 us; speedup vs baseline: 1.0643x; 1.0643x over previous
//
#include <hip/hip_runtime.h>
#include <stdint.h>

#define N_NODES 50000
#define M_PAD   50048   // 391*128
#define NIN     512
#define HDIM    512
#define DDIM    128
#define A_ADJ   3
#define E_EDGES 800000
#define TOT_E   (A_ADJ * E_EDGES)           // 2,400,000
#define TOT_ROWS (A_ADJ * N_NODES)          // 150,000
#define CB      49                          // coarse bins per adjacency (1024 rows each)
#define NB      (A_ADJ * CB)                // 147
#define CAP     17664                       // bin capacity: lambda=16384 + ~10 sigma
#define CHUNK   2048
#define NCHB    ((TOT_E + CHUNK - 1) / CHUNK)   // 1172
#define TRB     640                         // transpose blocks (163840/256)
#define DIB     25000                       // dropin blocks (6.4M/256)
#define G0NWG   (4 * (M_PAD / 128))         // 1564 gemm0 blocks

typedef __bf16 bf16x8 __attribute__((ext_vector_type(8)));
typedef float  f32x4  __attribute__((ext_vector_type(4)));
typedef const __attribute__((address_space(1))) void* gas1_t;
typedef __attribute__((address_space(3))) void* las3_t;

// ---------------- JAX threefry2x32 (bit-exact, partitionable mode) ----------------
__host__ __device__ inline void tf_round(uint32_t& x0, uint32_t& x1, int r) {
  x0 += x1; x1 = (x1 << r) | (x1 >> (32 - r)); x1 ^= x0;
}
__host__ __device__ inline void threefry2x32(uint32_t k0, uint32_t k1,
                                             uint32_t x0, uint32_t x1,
                                             uint32_t& o0, uint32_t& o1) {
  uint32_t ks2 = k0 ^ k1 ^ 0x1BD11BDAu;
  x0 += k0; x1 += k1;
  tf_round(x0,x1,13); tf_round(x0,x1,15); tf_round(x0,x1,26); tf_round(x0,x1,6);
  x0 += k1; x1 += ks2 + 1u;
  tf_round(x0,x1,17); tf_round(x0,x1,29); tf_round(x0,x1,16); tf_round(x0,x1,24);
  x0 += ks2; x1 += k0 + 2u;
  tf_round(x0,x1,13); tf_round(x0,x1,15); tf_round(x0,x1,26); tf_round(x0,x1,6);
  x0 += k0; x1 += k1 + 3u;
  tf_round(x0,x1,17); tf_round(x0,x1,29); tf_round(x0,x1,16); tf_round(x0,x1,24);
  x0 += k1; x1 += ks2 + 4u;
  tf_round(x0,x1,13); tf_round(x0,x1,15); tf_round(x0,x1,26); tf_round(x0,x1,6);
  x0 += ks2; x1 += k0 + 5u;
  o0 = x0; o1 = x1;
}

__device__ inline bool keep_bit(uint32_t b) {
  float f = __uint_as_float((b >> 9) | 0x3f800000u) - 1.0f;
  return f < 0.8f;
}
__device__ inline uint16_t f2bf(float f) {           // RNE float->bf16
  uint32_t u = __float_as_uint(f);
  return (uint16_t)((u + 0x7fffu + ((u >> 16) & 1u)) >> 16);
}
__device__ inline float bf2f(uint16_t b) { return __uint_as_float(((uint32_t)b) << 16); }

__device__ inline uint32_t rbits32(uint32_t ka, uint32_t kb, uint32_t i) {
  uint32_t o0, o1;
  threefry2x32(ka, kb, 0u, i, o0, o1);
  return o0 ^ o1;
}

// ---------------- GEMM body: 128x128 tile, 2-phase dbuf + source-side XOR swizzle ----------------
// MODE 0: relu -> bf16 h.  MODE 1: f32 h_a + fused drop2 -> bf16 hp0.
template <int MODE>
__device__ __forceinline__ void gemm_body(const uint16_t* __restrict__ A,
                                          const uint16_t* __restrict__ Bt,
                                          const float* __restrict__ bias,
                                          uint16_t* __restrict__ hOut,
                                          float* __restrict__ fOut,
                                          uint16_t* __restrict__ hp0,
                                          int Nn, int K, int bx, int by,
                                          char* smem, uint32_t ka, uint32_t kb) {
  uint16_t* As0 = (uint16_t*)smem;                    // 2 x 8 KB A, 2 x 8 KB B
  uint16_t* Bs0 = As0 + 8192;
  const int t  = threadIdx.x;
  const int w  = t >> 6, l = t & 63;
  const int lm = l & 15, kg = l >> 4;
  const int wr = w >> 1, wc = w & 1;
  const int rowbase = by * 128;
  const int colbase = bx * 128;
  const int c0 = t, c1 = t + 256;
  const int n0 = c0 >> 2, ch0 = (c0 & 3) ^ ((n0 >> 1) & 3);
  const int n1 = c1 >> 2, ch1 = (c1 & 3) ^ ((n1 >> 1) & 3);

  f32x4 acc[4][4] = {};

#define STAGEB(buf, kt)                                                             \
  {                                                                                 \
    __builtin_amdgcn_global_load_lds(                                               \
        (gas1_t)&A [(size_t)(rowbase + n0) * K + (kt) + ch0 * 8],                   \
        (las3_t)(As0 + (buf) * 4096 + c0 * 8), 16, 0, 0);                           \
    __builtin_amdgcn_global_load_lds(                                               \
        (gas1_t)&A [(size_t)(rowbase + n1) * K + (kt) + ch1 * 8],                   \
        (las3_t)(As0 + (buf) * 4096 + c1 * 8), 16, 0, 0);                           \
    __builtin_amdgcn_global_load_lds(                                               \
        (gas1_t)&Bt[(size_t)(colbase + n0) * K + (kt) + ch0 * 8],                   \
        (las3_t)(Bs0 + (buf) * 4096 + c0 * 8), 16, 0, 0);                           \
    __builtin_amdgcn_global_load_lds(                                               \
        (gas1_t)&Bt[(size_t)(colbase + n1) * K + (kt) + ch1 * 8],                   \
        (las3_t)(Bs0 + (buf) * 4096 + c1 * 8), 16, 0, 0);                           \
  }

  STAGEB(0, 0);
  asm volatile("s_waitcnt vmcnt(0)" ::: "memory");
  __syncthreads();

  const int NT = K >> 5;
  for (int tt = 0; tt < NT; ++tt) {
    const int cur = tt & 1;
    if (tt + 1 < NT) STAGEB(cur ^ 1, (tt + 1) * 32);

    const uint16_t* Asc = As0 + cur * 4096;
    const uint16_t* Bsc = Bs0 + cur * 4096;
    bf16x8 af[4], bfr[4];
#pragma unroll
    for (int m = 0; m < 4; ++m) {
      int ra = wr * 64 + m * 16 + lm;
      af[m] = *(const bf16x8*)&Asc[ra * 32 + ((kg ^ ((ra >> 1) & 3)) << 3)];
    }
#pragma unroll
    for (int n = 0; n < 4; ++n) {
      int rb = wc * 64 + n * 16 + lm;
      bfr[n] = *(const bf16x8*)&Bsc[rb * 32 + ((kg ^ ((rb >> 1) & 3)) << 3)];
    }
#pragma unroll
    for (int m = 0; m < 4; ++m)
#pragma unroll
      for (int n = 0; n < 4; ++n)
        acc[m][n] = __builtin_amdgcn_mfma_f32_16x16x32_bf16(af[m], bfr[n], acc[m][n], 0, 0, 0);

    asm volatile("s_waitcnt vmcnt(0)" ::: "memory");   // next-tile loads landed
    __syncthreads();                                   // all waves done with cur
  }
#undef STAGEB

#pragma unroll
  for (int m = 0; m < 4; ++m) {
    int r0 = rowbase + wr * 64 + m * 16 + kg * 4;
#pragma unroll
    for (int n = 0; n < 4; ++n) {
      int cc = colbase + wc * 64 + n * 16 + lm;
      float bv = bias[cc];
#pragma unroll
      for (int r = 0; r < 4; ++r) {
        int row = r0 + r;
        if (row < N_NODES) {
          float v = acc[m][n][r] + bv;
          if (MODE == 0) {
            hOut[(size_t)row * Nn + cc] = f2bf(fmaxf(v, 0.0f));
          } else {
            fOut[(size_t)row * Nn + cc] = v;
            uint32_t bits = rbits32(ka, kb, (uint32_t)(row * DDIM + cc));
            hp0[(size_t)row * DDIM + cc] = f2bf(keep_bit(bits) ? v * 1.25f : 0.0f);
          }
        }
      }
    }
  }
}

// ---------------- pass 1 body: chunk-sort 2048 edges into padded bin arenas ----------------
struct P1S {
  uint64_t lbuf[CHUNK];                               // 16384 B
  uint16_t lbkt[CHUNK];                               // 4096 B
  uint32_t hist[NB], scn[NB], lofs[NB], base[NB];     // 2352 B
  uint32_t hs[256];                                   // 1024 B
};                                                    // ~23.9 KB

__device__ __forceinline__ void pass1_body(const int* __restrict__ rows,
                                           const int* __restrict__ cols,
                                           const float* __restrict__ vals,
                                           uint32_t* __restrict__ gcur,
                                           uint64_t* __restrict__ sedgeA,
                                           int blk, char* smem) {
  P1S* S = (P1S*)smem;
  const int tid = threadIdx.x;
  const int cb = blk * CHUNK;
  const int cnt = min(CHUNK, TOT_E - cb);

  if (tid < NB) S->hist[tid] = 0;
  __syncthreads();

  uint64_t pay[8];
  uint16_t bk[8];
#pragma unroll
  for (int c = 0; c < 8; ++c) {
    int p = tid + c * 256;
    bk[c] = 0xffffu;
    if (p < cnt) {
      int e = cb + p;
      int a = e / E_EDGES;
      uint32_t r   = (uint32_t)rows[e];
      uint32_t col = (uint32_t)cols[e];
      float    v   = vals[e];
      uint16_t b = (uint16_t)(a * CB + (r >> 10));
      pay[c] = ((uint64_t)__float_as_uint(v) << 32) | ((r & 1023u) << 16) | col;
      bk[c]  = b;
      atomicAdd(&S->hist[b], 1u);
    }
  }
  __syncthreads();

  uint32_t hv = (tid < NB) ? S->hist[tid] : 0u;
  S->hs[tid] = hv;
  __syncthreads();
  for (int off = 1; off < 256; off <<= 1) {
    uint32_t v = (tid >= off) ? S->hs[tid - off] : 0u;
    __syncthreads();
    S->hs[tid] += v;
    __syncthreads();
  }
  if (tid < NB) {
    uint32_t excl = S->hs[tid] - hv;
    S->scn[tid]  = excl;
    S->lofs[tid] = excl;
    S->base[tid] = (uint32_t)tid * CAP + (hv ? atomicAdd(&gcur[tid], hv) : 0u);
  }
  __syncthreads();

#pragma unroll
  for (int c = 0; c < 8; ++c) {
    if (bk[c] != 0xffffu) {
      uint32_t p = atomicAdd(&S->lofs[bk[c]], 1u);
      S->lbuf[p] = pay[c];
      S->lbkt[p] = bk[c];
    }
  }
  __syncthreads();

#pragma unroll
  for (int c = 0; c < 8; ++c) {
    int p = tid + c * 256;
    if (p < cnt) {
      uint16_t k = S->lbkt[p];
      uint32_t slot = S->base[k] + ((uint32_t)p - S->scn[k]);
      if (slot < (uint32_t)(k + 1) * CAP)             // ~10-sigma guard, never taken
        sedgeA[slot] = S->lbuf[p];
    }
  }
}

// ---------------- pass 2 body: per bin, exact row sort -> u32 edges + offs/ends ----------------
struct P2S { uint32_t rh[1024], rs[1024], wsum[256]; };   // 9216 B

__device__ __forceinline__ void pass2_body(const uint32_t* __restrict__ gcur,
                                           const uint64_t* __restrict__ sedgeA,
                                           uint32_t* __restrict__ sedgeB,
                                           uint32_t* __restrict__ offs,
                                           uint32_t* __restrict__ ends,
                                           int b, char* smem) {
  P2S* S = (P2S*)smem;
  const int tid = threadIdx.x;
  const int a = b / CB, rb = (b % CB) * 1024;
  const int nrows = min(1024, N_NODES - rb);
  const uint32_t s0 = (uint32_t)b * CAP;
  uint32_t count = gcur[b];
  if (count > CAP) count = CAP;
  const uint32_t e0 = s0 + count;

#pragma unroll
  for (int c = 0; c < 4; ++c) S->rh[tid + c * 256] = 0;
  __syncthreads();
  for (uint32_t i = s0 + tid; i < e0; i += 256) {
    uint32_t rl = ((uint32_t)(sedgeA[i] >> 16)) & 1023u;
    atomicAdd(&S->rh[rl], 1u);
  }
  __syncthreads();

  uint32_t c0 = S->rh[tid * 4], c1 = S->rh[tid * 4 + 1];
  uint32_t c2 = S->rh[tid * 4 + 2], c3 = S->rh[tid * 4 + 3];
  uint32_t tsum = c0 + c1 + c2 + c3;
  S->wsum[tid] = tsum;
  __syncthreads();
  for (int off = 1; off < 256; off <<= 1) {
    uint32_t v = (tid >= off) ? S->wsum[tid - off] : 0u;
    __syncthreads();
    S->wsum[tid] += v;
    __syncthreads();
  }
  uint32_t run = S->wsum[tid] - tsum;
  S->rs[tid * 4] = run;     run += c0;
  S->rs[tid * 4 + 1] = run; run += c1;
  S->rs[tid * 4 + 2] = run; run += c2;
  S->rs[tid * 4 + 3] = run;
  __syncthreads();

  // per-row offs/ends (padded bases) + reset cursors
  for (int r = tid; r < 1024; r += 256) {
    if (r < nrows) {
      uint32_t st = s0 + S->rs[r];
      offs[(size_t)a * N_NODES + rb + r] = st;
      uint32_t cn = (r + 1 < 1024) ? (S->rs[r + 1] - S->rs[r]) : (count - S->rs[r]);
      ends[(size_t)a * N_NODES + rb + r] = st + cn;
    }
    S->rh[r] = S->rs[r];
  }
  __syncthreads();

  // exact scatter within the bin's span; convert to u32 {bf16 val | u16 col}
  for (uint32_t i = s0 + tid; i < e0; i += 256) {
    uint64_t ed = sedgeA[i];
    uint32_t rl = ((uint32_t)(ed >> 16)) & 1023u;
    uint32_t p = atomicAdd(&S->rh[rl], 1u);
    uint32_t vb = (uint32_t)f2bf(__uint_as_float((uint32_t)(ed >> 32)));
    sedgeB[s0 + p] = (vb << 16) | ((uint32_t)ed & 0xffffu);
  }
}

// ---------------- K1: transpose2 || pass1 || dropin (all independent) ----------------
__global__ __launch_bounds__(256) void k_front(const float* __restrict__ W1,
                                               uint16_t* __restrict__ w1t,
                                               const float* __restrict__ W2,
                                               uint16_t* __restrict__ w2t,
                                               const float* __restrict__ seq,
                                               uint16_t* __restrict__ x,
                                               const int* __restrict__ rows,
                                               const int* __restrict__ cols,
                                               const float* __restrict__ vals,
                                               uint32_t* __restrict__ gcur,
                                               uint64_t* __restrict__ sedgeA,
                                               uint32_t ka, uint32_t kb) {
  __shared__ __align__(16) char smem[24576];
  const int b = blockIdx.x, tid = threadIdx.x;
  if (b < TRB) {                                      // weight transposes
    int t = b * 256 + tid;
    const int T1 = (NIN * HDIM) / 2;
    if (t < T1) {
      int k2 = (2 * t) % NIN, n = (2 * t) / NIN;
      uint32_t p = (uint32_t)f2bf(W1[(size_t)k2 * HDIM + n])
                 | ((uint32_t)f2bf(W1[(size_t)(k2 + 1) * HDIM + n]) << 16);
      *(uint32_t*)&w1t[(size_t)n * NIN + k2] = p;
    } else {
      int u = t - T1;
      int k2 = (2 * u) % HDIM, n = (2 * u) / HDIM;
      uint32_t p = (uint32_t)f2bf(W2[(size_t)k2 * DDIM + n])
                 | ((uint32_t)f2bf(W2[(size_t)(k2 + 1) * DDIM + n]) << 16);
      *(uint32_t*)&w2t[(size_t)n * HDIM + k2] = p;
    }
  } else if (b < TRB + NCHB) {                        // edge partition pass 1
    pass1_body(rows, cols, vals, gcur, sedgeA, b - TRB, smem);
  } else {                                            // input dropout
    int t = (b - TRB - NCHB) * 256 + tid;             // < 6.4M exactly
    int i0 = 4 * t;
    float4 v = ((const float4*)seq)[t];
    float f[4] = {v.x, v.y, v.z, v.w};
    uint16_t r[4];
#pragma unroll
    for (int j = 0; j < 4; ++j) {
      uint32_t bits = rbits32(ka, kb, (uint32_t)(i0 + j));
      r[j] = f2bf(keep_bit(bits) ? f[j] * 1.25f : 0.0f);
    }
    uint2 w;
    w.x = (uint32_t)r[0] | ((uint32_t)r[1] << 16);
    w.y = (uint32_t)r[2] | ((uint32_t)r[3] << 16);
    ((uint2*)x)[t] = w;
  }
}

// ---------------- K2: gemm0 (bijective XCD chunk swizzle, m204) ----------------
__global__ __launch_bounds__(256) void k_mid(const uint16_t* __restrict__ x,
                                             const uint16_t* __restrict__ w1t,
                                             const float* __restrict__ b1,
                                             uint16_t* __restrict__ h) {
  __shared__ __align__(16) char smem[32768];
  // map hardware block id -> logical tile id so each XCD gets a CONTIGUOUS
  // chunk of logical ids (consecutive logical ids share the same x row-panel).
  const int q = G0NWG >> 3, r = G0NWG & 7;            // 195, 4
  int xcd = blockIdx.x & 7, o = blockIdx.x >> 3;
  int wg = (xcd < r) ? xcd * (q + 1) + o : r * (q + 1) + (xcd - r) * q + o;
  gemm_body<0>(x, w1t, b1, h, nullptr, nullptr, HDIM, NIN, wg & 3, wg >> 2, smem, 0u, 0u);
}

// ---------------- K3: gemm1(+drop2) || pass2 ----------------
__global__ __launch_bounds__(256) void k_back(const uint16_t* __restrict__ h,
                                              const uint16_t* __restrict__ w2t,
                                              const float* __restrict__ b2,
                                              float* __restrict__ ha,
                                              uint16_t* __restrict__ hp0,
                                              const uint32_t* __restrict__ gcur,
                                              const uint64_t* __restrict__ sedgeA,
                                              uint32_t* __restrict__ sedgeB,
                                              uint32_t* __restrict__ offs,
                                              uint32_t* __restrict__ ends,
                                              uint32_t ka, uint32_t kb) {
  __shared__ __align__(16) char smem[32768];
  const int b = blockIdx.x;
  if (b < M_PAD / 128)                                 // 391 gemm1 blocks
    gemm_body<1>(h, w2t, b2, nullptr, ha, hp0, DDIM, HDIM, 0, b, smem, ka, kb);
  else
    pass2_body(gcur, sedgeA, sedgeB, offs, ends, b - M_PAD / 128, smem);
}

// ---------------- SpMM+fusion: one wave per row, 2-deep gather (round-14 proven) ----------------
__global__ __launch_bounds__(256) void k_spmm_csr3(const uint32_t* __restrict__ offs,
                                                   const uint32_t* __restrict__ ends,
                                                   const uint32_t* __restrict__ sedge,
                                                   const uint16_t* __restrict__ hp0,
                                                   float* __restrict__ stack,
                                                   float* __restrict__ fus) {
  int row = (int)((blockIdx.x * (size_t)blockDim.x + threadIdx.x) >> 6);
  int l = threadIdx.x & 63;
  if (row >= N_NODES) return;
  const int q = l & 15, g = l >> 4;
  const char* hpb = (const char*)hp0;
  const uint32_t qoff = (uint32_t)(q << 4);           // 32-bit gather addressing
  float fs[8] = {};

#pragma unroll
  for (int a = 0; a < A_ADJ; ++a) {
    uint32_t s = offs[(size_t)a * N_NODES + row];
    uint32_t e = ends[(size_t)a * N_NODES + row];
    float acc[8] = {};
    for (uint32_t i = s; i < e; i += 8) {
      uint32_t i0 = i + g, i1 = i + 4 + g;
      float v0 = 0.f, v1 = 0.f;
      uint32_t o0 = qoff, o1 = qoff;
      if (i0 < e) { uint32_t ed = sedge[i0]; o0 += (ed & 0xffffu) << 8;
                    v0 = bf2f((uint16_t)(ed >> 16)); }
      if (i1 < e) { uint32_t ed = sedge[i1]; o1 += (ed & 0xffffu) << 8;
                    v1 = bf2f((uint16_t)(ed >> 16)); }
      uint4 p0 = *(const uint4*)(hpb + o0);
      uint4 p1 = *(const uint4*)(hpb + o1);
      acc[0] += bf2f((uint16_t)(p0.x & 0xffffu)) * v0;  acc[1] += bf2f((uint16_t)(p0.x >> 16)) * v0;
      acc[2] += bf2f((uint16_t)(p0.y & 0xffffu)) * v0;  acc[3] += bf2f((uint16_t)(p0.y >> 16)) * v0;
      acc[4] += bf2f((uint16_t)(p0.z & 0xffffu)) * v0;  acc[5] += bf2f((uint16_t)(p0.z >> 16)) * v0;
      acc[6] += bf2f((uint16_t)(p0.w & 0xffffu)) * v0;  acc[7] += bf2f((uint16_t)(p0.w >> 16)) * v0;
      acc[0] += bf2f((uint16_t)(p1.x & 0xffffu)) * v1;  acc[1] += bf2f((uint16_t)(p1.x >> 16)) * v1;
      acc[2] += bf2f((uint16_t)(p1.y & 0xffffu)) * v1;  acc[3] += bf2f((uint16_t)(p1.y >> 16)) * v1;
      acc[4] += bf2f((uint16_t)(p1.z & 0xffffu)) * v1;  acc[5] += bf2f((uint16_t)(p1.z >> 16)) * v1;
      acc[6] += bf2f((uint16_t)(p1.w & 0xffffu)) * v1;  acc[7] += bf2f((uint16_t)(p1.w >> 16)) * v1;
    }
#pragma unroll
    for (int d = 0; d < 8; ++d) {
      acc[d] += __shfl_xor(acc[d], 16);
      acc[d] += __shfl_xor(acc[d], 32);
    }
    if (l < 16) {
      size_t b4 = ((size_t)a * N_NODES + row) * 32 + (size_t)q * 2;
      ((float4*)stack)[b4]     = make_float4(acc[0], acc[1], acc[2], acc[3]);
      ((float4*)stack)[b4 + 1] = make_float4(acc[4], acc[5], acc[6], acc[7]);
    }
#pragma unroll
    for (int d = 0; d < 8; ++d) fs[d] += acc[d];
  }
  if (l < 16) {
    const float k3 = 1.0f / 3.0f;
    size_t b4 = (size_t)row * 32 + (size_t)q * 2;
    ((float4*)fus)[b4]     = make_float4(fs[0] * k3, fs[1] * k3, fs[2] * k3, fs[3] * k3);
    ((float4*)fus)[b4 + 1] = make_float4(fs[4] * k3, fs[5] * k3, fs[6] * k3, fs[7] * k3);
  }
}

extern "C" void kernel_launch(void* const* d_in, const int* in_sizes, int n_in,
                              void* d_out, int out_size, void* d_ws, size_t ws_size,
                              hipStream_t stream) {
  const float* seq  = (const float*)d_in[0];
  const float* W1   = (const float*)d_in[1];
  const float* b1   = (const float*)d_in[2];
  const float* W2   = (const float*)d_in[3];
  const float* b2   = (const float*)d_in[4];
  const float* vals = (const float*)d_in[5];
  const int*   rows = (const int*)d_in[6];
  const int*   cols = (const int*)d_in[7];

  float* out       = (float*)d_out;
  float* out_ha    = out;                                       // [N, D]
  float* out_stack = out + (size_t)N_NODES * DDIM;              // [A, N, D]
  float* out_fus   = out_stack + (size_t)A_ADJ * N_NODES * DDIM;

  uint16_t* x   = (uint16_t*)d_ws;                              // [M_PAD, NIN]  51.2 MB
  uint16_t* h   = x   + (size_t)M_PAD * NIN;                    // [M_PAD, HDIM] 51.2 MB
  uint16_t* w1t = h   + (size_t)M_PAD * HDIM;                   // [HDIM, NIN]
  uint16_t* w2t = w1t + (size_t)HDIM * NIN;                     // [DDIM, HDIM]
  uint16_t* hp0 = w2t + (size_t)DDIM * HDIM;                    // [N, D]
  uint32_t* gcur = (uint32_t*)(hp0 + (size_t)N_NODES * DDIM);   // [NB] (outside x!)
  uint32_t* offs = gcur + 256;                                  // [TOT_ROWS]
  uint32_t* ends = offs + TOT_ROWS;                             // [TOT_ROWS]

  // sedgeA (u64, padded arena 147*CAP = 20.8 MB) lives in d_out's stack region
  // (dead until spmm fully rewrites it); sedgeB (u32, 10.4 MB) aliases x
  // (dead after k_mid; pass2 runs in k_back).
  uint64_t* sedgeA = (uint64_t*)out_stack;
  uint32_t* sedgeB = (uint32_t*)x;

  // JAX partitionable-mode split of key (0,42)
  uint32_t k0a, k0b, k1a, k1b;
  threefry2x32(0u, 42u, 0u, 0u, k0a, k0b);
  threefry2x32(0u, 42u, 0u, 1u, k1a, k1b);

  (void)hipMemsetAsync(gcur, 0, NB * sizeof(uint32_t), stream);

  // K1: transposes || pass1 (padded-arena scatter) || dropin
  k_front<<<TRB + NCHB + DIB, 256, 0, stream>>>(W1, w1t, W2, w2t, seq, x,
                                                rows, cols, vals, gcur, sedgeA, k0a, k0b);

  // K2: gemm0 (XCD-chunked)
  k_mid<<<G0NWG, 256, 0, stream>>>(x, w1t, b1, h);

  // K3: gemm1(+drop2) || pass2
  k_back<<<(M_PAD / 128) + NB, 256, 0, stream>>>(h, w2t, b2, out_ha, hp0,
                                                 gcur, sedgeA, sedgeB, offs, ends, k1a, k1b);

  // SpMM + fused mean (overwrites the sedgeA region with real stack values)
  k_spmm_csr3<<<(N_NODES * 64 + 255) / 256, 256, 0, stream>>>(offs, ends, sedgeB, hp0,
                                                              out_stack, out_fus);
}